// Round 1
// baseline (384.448 us; speedup 1.0000x reference)
//
#include <hip/hip_runtime.h>

#define N_NODES 20000
#define N_EDGES 320000
#define DIM 128
#define NLAYER 3

// ---------------- CSR build ----------------

__global__ void zero_ints_kernel(int* __restrict__ p, int n) {
  int i = blockIdx.x * 256 + threadIdx.x;
  if (i < n) p[i] = 0;
}

__global__ void count_deg_kernel(const int* __restrict__ ei, int* __restrict__ deg) {
  int e = blockIdx.x * 256 + threadIdx.x;
  if (e < N_EDGES) atomicAdd(&deg[ei[N_EDGES + e]], 1);
}

// single-block exclusive scan over N_NODES degrees -> rowptr[0..N_NODES]
__global__ __launch_bounds__(1024) void scan_kernel(const int* __restrict__ deg,
                                                    int* __restrict__ rowptr) {
  __shared__ int wsum[16];
  __shared__ int carry_s;
  int t = threadIdx.x, lane = t & 63, w = t >> 6;
  if (t == 0) carry_s = 0;
  __syncthreads();
  for (int base = 0; base < N_NODES; base += 1024) {
    int i = base + t;
    int val = (i < N_NODES) ? deg[i] : 0;
    int s = val;
    #pragma unroll
    for (int off = 1; off < 64; off <<= 1) {
      int u = __shfl_up(s, off);
      if (lane >= off) s += u;
    }
    if (lane == 63) wsum[w] = s;
    __syncthreads();
    if (t < 16) {
      int wv = wsum[t];
      int ss = wv;
      #pragma unroll
      for (int off = 1; off < 16; off <<= 1) {
        int u = __shfl_up(ss, off);
        if (t >= off) ss += u;
      }
      wsum[t] = ss - wv;  // exclusive wave offset
    }
    __syncthreads();
    int excl = carry_s + wsum[w] + s - val;
    if (i < N_NODES) rowptr[i] = excl;
    __syncthreads();
    if (t == 1023) carry_s = excl + val;
    __syncthreads();
  }
  if (t == 0) rowptr[N_NODES] = carry_s;
}

__global__ void scatter_kernel(const int* __restrict__ ei, const int* __restrict__ rowptr,
                               int* __restrict__ cursor, int* __restrict__ csr_src) {
  int e = blockIdx.x * 256 + threadIdx.x;
  if (e < N_EDGES) {
    int d = ei[N_EDGES + e];
    int s = ei[e];
    int pos = atomicAdd(&cursor[d], 1);
    csr_src[rowptr[d] + pos] = s;
  }
}

// ---------------- fused 4-way GEMM: O_j = X @ W_j + b_j ----------------
// grid = (N_NODES/32, n_mats), block = 256. Tile: 32 rows x 128 cols.
// Per thread: 4 rows x 4 cols.
__global__ __launch_bounds__(256) void gemm_x4_kernel(
    const float* __restrict__ X,
    const float* __restrict__ W0, const float* __restrict__ B0, float* __restrict__ O0,
    const float* __restrict__ W1, const float* __restrict__ B1, float* __restrict__ O1,
    const float* __restrict__ W2, const float* __restrict__ B2, float* __restrict__ O2,
    const float* __restrict__ W3, const float* __restrict__ B3, float* __restrict__ O3) {
  __shared__ float xs[32][128];
  const float* W;
  const float* B;
  float* O;
  switch (blockIdx.y) {
    case 0: W = W0; B = B0; O = O0; break;
    case 1: W = W1; B = B1; O = O1; break;
    case 2: W = W2; B = B2; O = O2; break;
    default: W = W3; B = B3; O = O3; break;
  }
  int t = threadIdx.x;
  int row0 = blockIdx.x * 32;
  {
    const float4* Xv = (const float4*)(X + (size_t)row0 * DIM);
    float4* S = (float4*)&xs[0][0];
    S[t] = Xv[t];
    S[t + 256] = Xv[t + 256];
    S[t + 512] = Xv[t + 512];
    S[t + 768] = Xv[t + 768];
  }
  __syncthreads();
  int c4 = (t & 31) * 4;
  int r4 = (t >> 5) * 4;
  float acc[4][4];
  #pragma unroll
  for (int j = 0; j < 4; ++j)
    #pragma unroll
    for (int i = 0; i < 4; ++i) acc[j][i] = 0.f;
  for (int kk = 0; kk < DIM; kk += 4) {
    float4 xv[4];
    #pragma unroll
    for (int j = 0; j < 4; ++j) xv[j] = *(const float4*)&xs[r4 + j][kk];
    #pragma unroll
    for (int kq = 0; kq < 4; ++kq) {
      float4 wv = *(const float4*)(W + (size_t)(kk + kq) * DIM + c4);
      #pragma unroll
      for (int j = 0; j < 4; ++j) {
        float xj = (kq == 0) ? xv[j].x : (kq == 1) ? xv[j].y : (kq == 2) ? xv[j].z : xv[j].w;
        acc[j][0] = fmaf(xj, wv.x, acc[j][0]);
        acc[j][1] = fmaf(xj, wv.y, acc[j][1]);
        acc[j][2] = fmaf(xj, wv.z, acc[j][2]);
        acc[j][3] = fmaf(xj, wv.w, acc[j][3]);
      }
    }
  }
  float4 bias = *(const float4*)(B + c4);
  #pragma unroll
  for (int j = 0; j < 4; ++j) {
    float4 o;
    o.x = acc[j][0] + bias.x;
    o.y = acc[j][1] + bias.y;
    o.z = acc[j][2] + bias.z;
    o.w = acc[j][3] + bias.w;
    *(float4*)(O + (size_t)(row0 + r4 + j) * DIM + c4) = o;
  }
}

// ---------------- fused attention + beta-skip + relu + residual + layernorm --------
// one wave (64 threads) per dst node; lane l owns channels (2l, 2l+1); head = l/8
__global__ __launch_bounds__(64) void attn_fused_kernel(
    const float* __restrict__ q, const float* __restrict__ k, const float* __restrict__ v,
    const float* __restrict__ xr, const float* __restrict__ xres,
    const int* __restrict__ rowptr, const int* __restrict__ csr_src,
    const float* __restrict__ wbeta, const float* __restrict__ lng,
    const float* __restrict__ lnb, float* __restrict__ xnext) {
  int n = blockIdx.x;
  int lane = threadIdx.x;
  int c0 = lane * 2;
  float2 qv = *(const float2*)(q + (size_t)n * DIM + c0);
  int s0 = rowptr[n], s1 = rowptr[n + 1];
  float denom = 0.f, acc0 = 0.f, acc1 = 0.f;
  for (int base = s0; base < s1; base += 64) {
    int cnt = min(64, s1 - base);
    int sl = (base + lane < s1) ? csr_src[base + lane] : 0;
    for (int j = 0; j < cnt; ++j) {
      int src = __shfl(sl, j);
      const float2 kv = *(const float2*)(k + (size_t)src * DIM + c0);
      const float2 vv = *(const float2*)(v + (size_t)src * DIM + c0);
      float part = kv.x * qv.x + kv.y * qv.y;
      part += __shfl_xor(part, 1);
      part += __shfl_xor(part, 2);
      part += __shfl_xor(part, 4);
      // softmax without max-subtraction (mathematically identical after normalize;
      // alpha ~ N(0,1) here so exp cannot overflow)
      float ea = __expf(part * 0.25f);
      denom += ea;
      acc0 = fmaf(ea, vv.x, acc0);
      acc1 = fmaf(ea, vv.y, acc1);
    }
  }
  float inv = 1.f / (denom + 1e-16f);
  float o0 = acc0 * inv, o1 = acc1 * inv;
  float2 xrv = *(const float2*)(xr + (size_t)n * DIM + c0);
  // beta = sigmoid(out.(w1+w3) + xr.(w2-w3))
  float wa0 = wbeta[c0] + wbeta[2 * DIM + c0];
  float wa1 = wbeta[c0 + 1] + wbeta[2 * DIM + c0 + 1];
  float wb0 = wbeta[DIM + c0] - wbeta[2 * DIM + c0];
  float wb1 = wbeta[DIM + c0 + 1] - wbeta[2 * DIM + c0 + 1];
  float bs = o0 * wa0 + o1 * wa1 + xrv.x * wb0 + xrv.y * wb1;
  #pragma unroll
  for (int off = 1; off < 64; off <<= 1) bs += __shfl_xor(bs, off);
  float beta = 1.f / (1.f + __expf(-bs));
  float y0 = fmaxf(beta * xrv.x + (1.f - beta) * o0, 0.f);
  float y1 = fmaxf(beta * xrv.y + (1.f - beta) * o1, 0.f);
  float2 rv = *(const float2*)(xres + (size_t)n * DIM + c0);
  y0 += rv.x;
  y1 += rv.y;
  float s = y0 + y1;
  #pragma unroll
  for (int off = 1; off < 64; off <<= 1) s += __shfl_xor(s, off);
  float mu = s * (1.f / 128.f);
  float d0 = y0 - mu, d1 = y1 - mu;
  float vs = d0 * d0 + d1 * d1;
  #pragma unroll
  for (int off = 1; off < 64; off <<= 1) vs += __shfl_xor(vs, off);
  float rstd = rsqrtf(vs * (1.f / 128.f) + 1e-5f);
  float2 g = *(const float2*)(lng + c0);
  float2 b = *(const float2*)(lnb + c0);
  float2 o;
  o.x = d0 * rstd * g.x + b.x;
  o.y = d1 * rstd * g.y + b.y;
  *(float2*)(xnext + (size_t)n * DIM + c0) = o;
}

// ---------------- launch ----------------

extern "C" void kernel_launch(void* const* d_in, const int* in_sizes, int n_in,
                              void* d_out, int out_size, void* d_ws, size_t ws_size,
                              hipStream_t stream) {
  const float* x_in = (const float*)d_in[0];
  const int* ei = (const int*)d_in[1];
  const float* Wq = (const float*)d_in[2];
  const float* bq = (const float*)d_in[3];
  const float* Wk = (const float*)d_in[4];
  const float* bk = (const float*)d_in[5];
  const float* Wv = (const float*)d_in[6];
  const float* bv = (const float*)d_in[7];
  const float* Wsk = (const float*)d_in[8];
  const float* bsk = (const float*)d_in[9];
  const float* Wb = (const float*)d_in[10];
  const float* lng = (const float*)d_in[11];
  const float* lnb = (const float*)d_in[12];
  const float* Wout = (const float*)d_in[13];
  const float* bout = (const float*)d_in[14];
  float* out = (float*)d_out;

  char* p = (char*)d_ws;
  auto alloc = [&](size_t bytes) {
    char* r = p;
    p += (bytes + 255) & ~(size_t)255;
    return r;
  };
  float* qb = (float*)alloc((size_t)N_NODES * DIM * 4);
  float* kb = (float*)alloc((size_t)N_NODES * DIM * 4);
  float* vb = (float*)alloc((size_t)N_NODES * DIM * 4);
  float* xrb = (float*)alloc((size_t)N_NODES * DIM * 4);
  float* xb0 = (float*)alloc((size_t)N_NODES * DIM * 4);
  int* rowptr = (int*)alloc((N_NODES + 1) * 4);
  int* degc = (int*)alloc(N_NODES * 4);
  int* csr_src = (int*)alloc(N_EDGES * 4);
  float* xb1 = out;  // d_out doubles as the layer-1 x buffer

  // CSR by dst (edge_index is a fixed input; rebuilt every call for determinism
  // of the capture graph)
  zero_ints_kernel<<<(N_NODES + 255) / 256, 256, 0, stream>>>(degc, N_NODES);
  count_deg_kernel<<<(N_EDGES + 255) / 256, 256, 0, stream>>>(ei, degc);
  scan_kernel<<<1, 1024, 0, stream>>>(degc, rowptr);
  zero_ints_kernel<<<(N_NODES + 255) / 256, 256, 0, stream>>>(degc, N_NODES);
  scatter_kernel<<<(N_EDGES + 255) / 256, 256, 0, stream>>>(ei, rowptr, degc, csr_src);

  const float* xc = x_in;
  float* bufs[NLAYER] = {xb0, xb1, xb0};
  for (int l = 0; l < NLAYER; ++l) {
    gemm_x4_kernel<<<dim3(N_NODES / 32, 4), 256, 0, stream>>>(
        xc,
        Wq + (size_t)l * DIM * DIM, bq + (size_t)l * DIM, qb,
        Wk + (size_t)l * DIM * DIM, bk + (size_t)l * DIM, kb,
        Wv + (size_t)l * DIM * DIM, bv + (size_t)l * DIM, vb,
        Wsk + (size_t)l * DIM * DIM, bsk + (size_t)l * DIM, xrb);
    attn_fused_kernel<<<N_NODES, 64, 0, stream>>>(
        qb, kb, vb, xrb, xc, rowptr, csr_src,
        Wb + (size_t)l * 3 * DIM, lng + (size_t)l * DIM, lnb + (size_t)l * DIM,
        bufs[l]);
    xc = bufs[l];
  }
  // final projection: out = x @ Wout + bout  (grid.y = 1 -> only slot 0 used)
  gemm_x4_kernel<<<dim3(N_NODES / 32, 1), 256, 0, stream>>>(
      xc, Wout, bout, out, Wout, bout, out, Wout, bout, out, Wout, bout, out);
}

// Round 2
// 286.891 us; speedup vs baseline: 1.3401x; 1.3401x over previous
//
#include <hip/hip_runtime.h>

#define N_NODES 20000
#define N_EDGES 320000
#define DIM 128
#define NLAYER 3

typedef __attribute__((ext_vector_type(8))) short short8;
typedef __attribute__((ext_vector_type(4))) float f32x4;

__device__ inline ushort f2bf(float f) {
  uint u = __float_as_uint(f);
  uint r = (u + 0x7fffu + ((u >> 16) & 1u)) >> 16;
  return (ushort)r;
}
__device__ inline float bf2f(ushort u) { return __uint_as_float(((uint)u) << 16); }

// ---------------- CSR build ----------------

__global__ void zero_ints_kernel(int* __restrict__ p, int n) {
  int i = blockIdx.x * 256 + threadIdx.x;
  if (i < n) p[i] = 0;
}

__global__ void count_deg_kernel(const int* __restrict__ ei, int* __restrict__ deg) {
  int e = blockIdx.x * 256 + threadIdx.x;
  if (e < N_EDGES) atomicAdd(&deg[ei[N_EDGES + e]], 1);
}

__global__ __launch_bounds__(1024) void scan_kernel(const int* __restrict__ deg,
                                                    int* __restrict__ rowptr) {
  __shared__ int wsum[16];
  __shared__ int carry_s;
  int t = threadIdx.x, lane = t & 63, w = t >> 6;
  if (t == 0) carry_s = 0;
  __syncthreads();
  for (int base = 0; base < N_NODES; base += 1024) {
    int i = base + t;
    int val = (i < N_NODES) ? deg[i] : 0;
    int s = val;
    #pragma unroll
    for (int off = 1; off < 64; off <<= 1) {
      int u = __shfl_up(s, off);
      if (lane >= off) s += u;
    }
    if (lane == 63) wsum[w] = s;
    __syncthreads();
    if (t < 16) {
      int wv = wsum[t];
      int ss = wv;
      #pragma unroll
      for (int off = 1; off < 16; off <<= 1) {
        int u = __shfl_up(ss, off);
        if (t >= off) ss += u;
      }
      wsum[t] = ss - wv;
    }
    __syncthreads();
    int excl = carry_s + wsum[w] + s - val;
    if (i < N_NODES) rowptr[i] = excl;
    __syncthreads();
    if (t == 1023) carry_s = excl + val;
    __syncthreads();
  }
  if (t == 0) rowptr[N_NODES] = carry_s;
}

__global__ void scatter_kernel(const int* __restrict__ ei, const int* __restrict__ rowptr,
                               int* __restrict__ cursor, int* __restrict__ csr_src) {
  int e = blockIdx.x * 256 + threadIdx.x;
  if (e < N_EDGES) {
    int d = ei[N_EDGES + e];
    int s = ei[e];
    int pos = atomicAdd(&cursor[d], 1);
    csr_src[rowptr[d] + pos] = s;
  }
}

// ---------------- casts ----------------

__global__ void cast_x_kernel(const float* __restrict__ x, ushort* __restrict__ xb, int n4) {
  int i = blockIdx.x * 256 + threadIdx.x;
  if (i < n4) {
    float4 f = ((const float4*)x)[i];
    ushort4 o;
    o.x = f2bf(f.x); o.y = f2bf(f.y); o.z = f2bf(f.z); o.w = f2bf(f.w);
    ((ushort4*)xb)[i] = o;
  }
}

// cast + transpose weights: wt[z][n][k] = (float)W_z[k][n], z = l*4+{q,k,v,skip}, z=12 -> Wout
__global__ void cast_w_kernel(const float* __restrict__ Wq, const float* __restrict__ Wk,
                              const float* __restrict__ Wv, const float* __restrict__ Ws,
                              const float* __restrict__ Wo, ushort* __restrict__ wt) {
  int z = blockIdx.z;
  const float* src;
  if (z < 12) {
    int l = z >> 2, j = z & 3;
    src = (j == 0 ? Wq : j == 1 ? Wk : j == 2 ? Wv : Ws) + (size_t)l * DIM * DIM;
  } else {
    src = Wo;
  }
  __shared__ float tile[32][33];
  int tx = threadIdx.x, ty = threadIdx.y;  // 32 x 8
  int k0 = blockIdx.x * 32, n0 = blockIdx.y * 32;
  #pragma unroll
  for (int i = 0; i < 32; i += 8)
    tile[ty + i][tx] = src[(size_t)(k0 + ty + i) * DIM + n0 + tx];
  __syncthreads();
  ushort* dst = wt + (size_t)z * DIM * DIM;
  #pragma unroll
  for (int i = 0; i < 32; i += 8)
    dst[(size_t)(n0 + ty + i) * DIM + k0 + tx] = f2bf(tile[tx][ty + i]);
}

// ---------------- bf16 MFMA GEMM: O_j = X @ W_j + b_j ----------------
// grid (ceil(M/64), nmat), block 256 (4 waves, 2x2). Wave tile 32x64 = 2x4 frags 16x16.
// X: [M][128] bf16 row-major. WT: [nmat][128][128] bf16, WT[n][k] = W[k][n].
template <int OUT_BF16>
__global__ __launch_bounds__(256) void gemm_mfma_kernel(
    const ushort* __restrict__ X, const ushort* __restrict__ WT,
    const float* __restrict__ B0, const float* __restrict__ B1,
    const float* __restrict__ B2, const float* __restrict__ B3,
    void* __restrict__ O0, void* __restrict__ O1, void* __restrict__ O2,
    void* __restrict__ O3) {
  int mat = blockIdx.y;
  const ushort* Wt = WT + (size_t)mat * DIM * DIM;
  const float* bias;
  void* O;
  switch (mat) {
    case 0: bias = B0; O = O0; break;
    case 1: bias = B1; O = O1; break;
    case 2: bias = B2; O = O2; break;
    default: bias = B3; O = O3; break;
  }
  int t = threadIdx.x;
  int wid = t >> 6, lane = t & 63;
  int row0 = blockIdx.x * 64 + (wid >> 1) * 32;
  int col0 = (wid & 1) * 64;
  int lr = lane & 15;
  int kc = (lane >> 4) * 8;

  f32x4 acc[2][4];
  #pragma unroll
  for (int i = 0; i < 2; ++i)
    #pragma unroll
    for (int j = 0; j < 4; ++j) acc[i][j] = (f32x4){0.f, 0.f, 0.f, 0.f};

  #pragma unroll
  for (int kb = 0; kb < DIM; kb += 32) {
    short8 a[2], b[4];
    #pragma unroll
    for (int rf = 0; rf < 2; ++rf) {
      int r = row0 + rf * 16 + lr;
      r = min(r, N_NODES - 1);
      a[rf] = *(const short8*)(X + (size_t)r * DIM + kb + kc);
    }
    #pragma unroll
    for (int cf = 0; cf < 4; ++cf) {
      int c = col0 + cf * 16 + lr;
      b[cf] = *(const short8*)(Wt + (size_t)c * DIM + kb + kc);
    }
    #pragma unroll
    for (int rf = 0; rf < 2; ++rf)
      #pragma unroll
      for (int cf = 0; cf < 4; ++cf)
        acc[rf][cf] = __builtin_amdgcn_mfma_f32_16x16x32_bf16(a[rf], b[cf], acc[rf][cf], 0, 0, 0);
  }

  // C/D layout: col = lane&15, row = (lane>>4)*4 + reg  [m89-verified]
  #pragma unroll
  for (int cf = 0; cf < 4; ++cf) {
    int c = col0 + cf * 16 + lr;
    float bv = bias[c];
    #pragma unroll
    for (int rf = 0; rf < 2; ++rf) {
      #pragma unroll
      for (int reg = 0; reg < 4; ++reg) {
        int r = row0 + rf * 16 + (lane >> 4) * 4 + reg;
        if (r < N_NODES) {
          float val = acc[rf][cf][reg] + bv;
          if (OUT_BF16)
            ((ushort*)O)[(size_t)r * DIM + c] = f2bf(val);
          else
            ((float*)O)[(size_t)r * DIM + c] = val;
        }
      }
    }
  }
}

// ---------------- fused attention + beta-skip + relu + residual + layernorm --------
// one wave per dst node; lane l owns channels (2l, 2l+1); head = l/8
__global__ __launch_bounds__(64) void attn_fused_kernel(
    const ushort* __restrict__ q, const ushort* __restrict__ k, const ushort* __restrict__ v,
    const ushort* __restrict__ xr, const float* __restrict__ xres,
    const int* __restrict__ rowptr, const int* __restrict__ csr_src,
    const float* __restrict__ wbeta, const float* __restrict__ lng,
    const float* __restrict__ lnb, float* __restrict__ xnext,
    ushort* __restrict__ xnextb) {
  int n = blockIdx.x;
  int lane = threadIdx.x;
  int c0 = lane * 2;
  ushort2 qu = *(const ushort2*)(q + (size_t)n * DIM + c0);
  float q0 = bf2f(qu.x), q1 = bf2f(qu.y);
  int s0 = rowptr[n], s1 = rowptr[n + 1];
  float denom = 0.f, acc0 = 0.f, acc1 = 0.f;
  for (int base = s0; base < s1; base += 64) {
    int cnt = min(64, s1 - base);
    int sl = (base + lane < s1) ? csr_src[base + lane] : 0;
    for (int j = 0; j < cnt; ++j) {
      int src = __shfl(sl, j);
      ushort2 ku = *(const ushort2*)(k + (size_t)src * DIM + c0);
      ushort2 vu = *(const ushort2*)(v + (size_t)src * DIM + c0);
      float part = bf2f(ku.x) * q0 + bf2f(ku.y) * q1;
      part += __shfl_xor(part, 1);
      part += __shfl_xor(part, 2);
      part += __shfl_xor(part, 4);
      float ea = __expf(part * 0.25f);
      denom += ea;
      acc0 = fmaf(ea, bf2f(vu.x), acc0);
      acc1 = fmaf(ea, bf2f(vu.y), acc1);
    }
  }
  float inv = 1.f / (denom + 1e-16f);
  float o0 = acc0 * inv, o1 = acc1 * inv;
  ushort2 xru = *(const ushort2*)(xr + (size_t)n * DIM + c0);
  float xr0 = bf2f(xru.x), xr1 = bf2f(xru.y);
  float wa0 = wbeta[c0] + wbeta[2 * DIM + c0];
  float wa1 = wbeta[c0 + 1] + wbeta[2 * DIM + c0 + 1];
  float wb0 = wbeta[DIM + c0] - wbeta[2 * DIM + c0];
  float wb1 = wbeta[DIM + c0 + 1] - wbeta[2 * DIM + c0 + 1];
  float bs = o0 * wa0 + o1 * wa1 + xr0 * wb0 + xr1 * wb1;
  #pragma unroll
  for (int off = 1; off < 64; off <<= 1) bs += __shfl_xor(bs, off);
  float beta = 1.f / (1.f + __expf(-bs));
  float y0 = fmaxf(beta * xr0 + (1.f - beta) * o0, 0.f);
  float y1 = fmaxf(beta * xr1 + (1.f - beta) * o1, 0.f);
  float2 rv = *(const float2*)(xres + (size_t)n * DIM + c0);
  y0 += rv.x;
  y1 += rv.y;
  float s = y0 + y1;
  #pragma unroll
  for (int off = 1; off < 64; off <<= 1) s += __shfl_xor(s, off);
  float mu = s * (1.f / 128.f);
  float d0 = y0 - mu, d1 = y1 - mu;
  float vs = d0 * d0 + d1 * d1;
  #pragma unroll
  for (int off = 1; off < 64; off <<= 1) vs += __shfl_xor(vs, off);
  float rstd = rsqrtf(vs * (1.f / 128.f) + 1e-5f);
  float2 g = *(const float2*)(lng + c0);
  float2 b = *(const float2*)(lnb + c0);
  float out0 = d0 * rstd * g.x + b.x;
  float out1 = d1 * rstd * g.y + b.y;
  *(float2*)(xnext + (size_t)n * DIM + c0) = make_float2(out0, out1);
  ushort2 ob;
  ob.x = f2bf(out0);
  ob.y = f2bf(out1);
  *(ushort2*)(xnextb + (size_t)n * DIM + c0) = ob;
}

// ---------------- launch ----------------

extern "C" void kernel_launch(void* const* d_in, const int* in_sizes, int n_in,
                              void* d_out, int out_size, void* d_ws, size_t ws_size,
                              hipStream_t stream) {
  const float* x_in = (const float*)d_in[0];
  const int* ei = (const int*)d_in[1];
  const float* Wq = (const float*)d_in[2];
  const float* bq = (const float*)d_in[3];
  const float* Wk = (const float*)d_in[4];
  const float* bk = (const float*)d_in[5];
  const float* Wv = (const float*)d_in[6];
  const float* bv = (const float*)d_in[7];
  const float* Wsk = (const float*)d_in[8];
  const float* bsk = (const float*)d_in[9];
  const float* Wb = (const float*)d_in[10];
  const float* lng = (const float*)d_in[11];
  const float* lnb = (const float*)d_in[12];
  const float* Wout = (const float*)d_in[13];
  const float* bout = (const float*)d_in[14];
  float* out = (float*)d_out;

  char* p = (char*)d_ws;
  auto alloc = [&](size_t bytes) {
    char* r = p;
    p += (bytes + 255) & ~(size_t)255;
    return r;
  };
  const size_t NB2 = (size_t)N_NODES * DIM * 2;  // bf16 node matrix
  const size_t NB4 = (size_t)N_NODES * DIM * 4;  // fp32 node matrix
  ushort* xbb = (ushort*)alloc(NB2);   // current x, bf16 (GEMM input)
  ushort* qb = (ushort*)alloc(NB2);
  ushort* kb = (ushort*)alloc(NB2);
  ushort* vb = (ushort*)alloc(NB2);
  ushort* xrb = (ushort*)alloc(NB2);
  float* xf0 = (float*)alloc(NB4);     // fp32 x ping-pong (residual path)
  float* xf1 = (float*)alloc(NB4);
  ushort* wt = (ushort*)alloc((size_t)13 * DIM * DIM * 2);
  int* rowptr = (int*)alloc((N_NODES + 1) * 4);
  int* degc = (int*)alloc(N_NODES * 4);
  int* csr_src = (int*)alloc(N_EDGES * 4);

  // CSR by dst
  zero_ints_kernel<<<(N_NODES + 255) / 256, 256, 0, stream>>>(degc, N_NODES);
  count_deg_kernel<<<(N_EDGES + 255) / 256, 256, 0, stream>>>(ei, degc);
  scan_kernel<<<1, 1024, 0, stream>>>(degc, rowptr);
  zero_ints_kernel<<<(N_NODES + 255) / 256, 256, 0, stream>>>(degc, N_NODES);
  scatter_kernel<<<(N_EDGES + 255) / 256, 256, 0, stream>>>(ei, rowptr, degc, csr_src);

  // casts
  cast_x_kernel<<<(N_NODES * DIM / 4 + 255) / 256, 256, 0, stream>>>(x_in, xbb,
                                                                     N_NODES * DIM / 4);
  cast_w_kernel<<<dim3(4, 4, 13), dim3(32, 8), 0, stream>>>(Wq, Wk, Wv, Wsk, Wout, wt);

  const int GX = (N_NODES + 63) / 64;  // 313
  const float* xres = x_in;
  float* xfbufs[NLAYER] = {xf0, xf1, xf0};
  for (int l = 0; l < NLAYER; ++l) {
    gemm_mfma_kernel<1><<<dim3(GX, 4), 256, 0, stream>>>(
        xbb, wt + (size_t)l * 4 * DIM * DIM,
        bq + (size_t)l * DIM, bk + (size_t)l * DIM, bv + (size_t)l * DIM,
        bsk + (size_t)l * DIM, qb, kb, vb, xrb);
    attn_fused_kernel<<<N_NODES, 64, 0, stream>>>(
        qb, kb, vb, xrb, xres, rowptr, csr_src,
        Wb + (size_t)l * 3 * DIM, lng + (size_t)l * DIM, lnb + (size_t)l * DIM,
        xfbufs[l], xbb);
    xres = xfbufs[l];
  }
  // final projection (fp32 out to d_out)
  gemm_mfma_kernel<0><<<dim3(GX, 1), 256, 0, stream>>>(
      xbb, wt + (size_t)12 * DIM * DIM, bout, bout, bout, bout, out, out, out, out);
}

// Round 3
// 240.763 us; speedup vs baseline: 1.5968x; 1.1916x over previous
//
#include <hip/hip_runtime.h>

#define N_NODES 20000
#define N_EDGES 320000
#define DIM 128
#define NLAYER 3
#define SCAN_BLK 1024
#define N_SCAN_BLKS ((N_NODES + SCAN_BLK - 1) / SCAN_BLK)  // 20

typedef __attribute__((ext_vector_type(8))) short short8;
typedef __attribute__((ext_vector_type(4))) float f32x4;

__device__ inline ushort f2bf(float f) {
  uint u = __float_as_uint(f);
  uint r = (u + 0x7fffu + ((u >> 16) & 1u)) >> 16;
  return (ushort)r;
}
__device__ inline float bf2f(ushort u) { return __uint_as_float(((uint)u) << 16); }

// ---------------- CSR build ----------------

__global__ void zero_ints_kernel(int* __restrict__ p, int n) {
  int i = blockIdx.x * 256 + threadIdx.x;
  if (i < n) p[i] = 0;
}

__global__ void count_deg_kernel(const int* __restrict__ ei, int* __restrict__ deg) {
  int e = blockIdx.x * 256 + threadIdx.x;
  if (e < N_EDGES) atomicAdd(&deg[ei[N_EDGES + e]], 1);
}

// deterministic 3-phase exclusive scan of deg -> rowptr
__global__ __launch_bounds__(SCAN_BLK) void scan1_kernel(const int* __restrict__ deg,
                                                         int* __restrict__ rowptr,
                                                         int* __restrict__ blksum) {
  __shared__ int wsum[16];
  int t = threadIdx.x, lane = t & 63, w = t >> 6;
  int i = blockIdx.x * SCAN_BLK + t;
  int val = (i < N_NODES) ? deg[i] : 0;
  int s = val;
  #pragma unroll
  for (int off = 1; off < 64; off <<= 1) {
    int u = __shfl_up(s, off);
    if (lane >= off) s += u;
  }
  if (lane == 63) wsum[w] = s;
  __syncthreads();
  if (t < 16) {
    int wv = wsum[t];
    int ss = wv;
    #pragma unroll
    for (int off = 1; off < 16; off <<= 1) {
      int u = __shfl_up(ss, off);
      if (t >= off) ss += u;
    }
    wsum[t] = ss - wv;  // exclusive wave offset
  }
  __syncthreads();
  int excl = wsum[w] + s - val;
  if (i < N_NODES) rowptr[i] = excl;
  if (t == SCAN_BLK - 1) blksum[blockIdx.x] = excl + val;
}

__global__ void scan2_kernel(int* __restrict__ blksum, int* __restrict__ rowptr) {
  int t = threadIdx.x;  // 64 threads
  int val = (t < N_SCAN_BLKS) ? blksum[t] : 0;
  int s = val;
  #pragma unroll
  for (int off = 1; off < 64; off <<= 1) {
    int u = __shfl_up(s, off);
    if (t >= off) s += u;
  }
  if (t < N_SCAN_BLKS) blksum[t] = s - val;  // exclusive block offset
  if (t == 63) rowptr[N_NODES] = s;          // grand total
}

__global__ __launch_bounds__(SCAN_BLK) void scan3_kernel(int* __restrict__ rowptr,
                                                         const int* __restrict__ blksum) {
  int i = blockIdx.x * SCAN_BLK + threadIdx.x;
  if (i < N_NODES) rowptr[i] += blksum[blockIdx.x];
}

__global__ void scatter_kernel(const int* __restrict__ ei, const int* __restrict__ rowptr,
                               int* __restrict__ cursor, int* __restrict__ csr_src) {
  int e = blockIdx.x * 256 + threadIdx.x;
  if (e < N_EDGES) {
    int d = ei[N_EDGES + e];
    int s = ei[e];
    int pos = atomicAdd(&cursor[d], 1);
    csr_src[rowptr[d] + pos] = s;
  }
}

// ---------------- casts ----------------

__global__ void cast_x_kernel(const float* __restrict__ x, ushort* __restrict__ xb, int n4) {
  int i = blockIdx.x * 256 + threadIdx.x;
  if (i < n4) {
    float4 f = ((const float4*)x)[i];
    ushort4 o;
    o.x = f2bf(f.x); o.y = f2bf(f.y); o.z = f2bf(f.z); o.w = f2bf(f.w);
    ((ushort4*)xb)[i] = o;
  }
}

__global__ void cast_w_kernel(const float* __restrict__ Wq, const float* __restrict__ Wk,
                              const float* __restrict__ Wv, const float* __restrict__ Ws,
                              const float* __restrict__ Wo, ushort* __restrict__ wt) {
  int z = blockIdx.z;
  const float* src;
  if (z < 12) {
    int l = z >> 2, j = z & 3;
    src = (j == 0 ? Wq : j == 1 ? Wk : j == 2 ? Wv : Ws) + (size_t)l * DIM * DIM;
  } else {
    src = Wo;
  }
  __shared__ float tile[32][33];
  int tx = threadIdx.x, ty = threadIdx.y;  // 32 x 8
  int k0 = blockIdx.x * 32, n0 = blockIdx.y * 32;
  #pragma unroll
  for (int i = 0; i < 32; i += 8)
    tile[ty + i][tx] = src[(size_t)(k0 + ty + i) * DIM + n0 + tx];
  __syncthreads();
  ushort* dst = wt + (size_t)z * DIM * DIM;
  #pragma unroll
  for (int i = 0; i < 32; i += 8)
    dst[(size_t)(n0 + ty + i) * DIM + k0 + tx] = f2bf(tile[tx][ty + i]);
}

// ---------------- bf16 MFMA GEMM (unchanged from round 2) ----------------
template <int OUT_BF16>
__global__ __launch_bounds__(256) void gemm_mfma_kernel(
    const ushort* __restrict__ X, const ushort* __restrict__ WT,
    const float* __restrict__ B0, const float* __restrict__ B1,
    const float* __restrict__ B2, const float* __restrict__ B3,
    void* __restrict__ O0, void* __restrict__ O1, void* __restrict__ O2,
    void* __restrict__ O3) {
  int mat = blockIdx.y;
  const ushort* Wt = WT + (size_t)mat * DIM * DIM;
  const float* bias;
  void* O;
  switch (mat) {
    case 0: bias = B0; O = O0; break;
    case 1: bias = B1; O = O1; break;
    case 2: bias = B2; O = O2; break;
    default: bias = B3; O = O3; break;
  }
  int t = threadIdx.x;
  int wid = t >> 6, lane = t & 63;
  int row0 = blockIdx.x * 64 + (wid >> 1) * 32;
  int col0 = (wid & 1) * 64;
  int lr = lane & 15;
  int kc = (lane >> 4) * 8;

  f32x4 acc[2][4];
  #pragma unroll
  for (int i = 0; i < 2; ++i)
    #pragma unroll
    for (int j = 0; j < 4; ++j) acc[i][j] = (f32x4){0.f, 0.f, 0.f, 0.f};

  #pragma unroll
  for (int kb = 0; kb < DIM; kb += 32) {
    short8 a[2], b[4];
    #pragma unroll
    for (int rf = 0; rf < 2; ++rf) {
      int r = row0 + rf * 16 + lr;
      r = min(r, N_NODES - 1);
      a[rf] = *(const short8*)(X + (size_t)r * DIM + kb + kc);
    }
    #pragma unroll
    for (int cf = 0; cf < 4; ++cf) {
      int c = col0 + cf * 16 + lr;
      b[cf] = *(const short8*)(Wt + (size_t)c * DIM + kb + kc);
    }
    #pragma unroll
    for (int rf = 0; rf < 2; ++rf)
      #pragma unroll
      for (int cf = 0; cf < 4; ++cf)
        acc[rf][cf] = __builtin_amdgcn_mfma_f32_16x16x32_bf16(a[rf], b[cf], acc[rf][cf], 0, 0, 0);
  }

  #pragma unroll
  for (int cf = 0; cf < 4; ++cf) {
    int c = col0 + cf * 16 + lr;
    float bv = bias[c];
    #pragma unroll
    for (int rf = 0; rf < 2; ++rf) {
      #pragma unroll
      for (int reg = 0; reg < 4; ++reg) {
        int r = row0 + rf * 16 + (lane >> 4) * 4 + reg;
        if (r < N_NODES) {
          float val = acc[rf][cf][reg] + bv;
          if (OUT_BF16)
            ((ushort*)O)[(size_t)r * DIM + c] = f2bf(val);
          else
            ((float*)O)[(size_t)r * DIM + c] = val;
        }
      }
    }
  }
}

// ---------------- fused attention + beta-skip + relu + residual + layernorm --------
// one wave per dst node. Edge phase: lane = (e = lane>>3, h = lane&7); each lane
// computes full per-(edge,head) dots over C=16 channels -> 8 edges in flight,
// no cross-lane ops per edge. Per-node 3-round xor-reduce + LDS handoff to the
// channel-per-lane epilogue layout.
__global__ __launch_bounds__(64) void attn_fused_kernel(
    const ushort* __restrict__ q, const ushort* __restrict__ k, const ushort* __restrict__ v,
    const ushort* __restrict__ xr, const float* __restrict__ xres,
    const int* __restrict__ rowptr, const int* __restrict__ csr_src,
    const float* __restrict__ wbeta, const float* __restrict__ lng,
    const float* __restrict__ lnb, float* __restrict__ xnext,
    ushort* __restrict__ xnextb) {
  __shared__ float lds_s[8][20];
  int n = blockIdx.x;
  int lane = threadIdx.x;
  int h = lane & 7, e = lane >> 3;

  // q slice for head h: 16 channels -> fp32 regs
  const ushort* qrow = q + (size_t)n * DIM + h * 16;
  short8 q0 = *(const short8*)qrow;
  short8 q1 = *(const short8*)(qrow + 8);
  float qf[16];
  #pragma unroll
  for (int i = 0; i < 8; ++i) {
    qf[i] = bf2f((ushort)q0[i]);
    qf[8 + i] = bf2f((ushort)q1[i]);
  }

  int s0 = rowptr[n];
  int deg = rowptr[n + 1] - s0;
  float acc[16];
  #pragma unroll
  for (int i = 0; i < 16; ++i) acc[i] = 0.f;
  float dsum = 0.f;

  for (int base = 0; base < deg; base += 8) {
    int idx = base + e;
    bool valid = idx < deg;
    int src = csr_src[s0 + min(idx, deg - 1)];
    const ushort* kr = k + (size_t)src * DIM + h * 16;
    const ushort* vr = v + (size_t)src * DIM + h * 16;
    short8 ka = *(const short8*)kr;
    short8 kb2 = *(const short8*)(kr + 8);
    short8 va = *(const short8*)vr;
    short8 vb2 = *(const short8*)(vr + 8);
    float p0 = 0.f, p1 = 0.f;
    #pragma unroll
    for (int i = 0; i < 8; ++i) {
      p0 = fmaf(qf[i], bf2f((ushort)ka[i]), p0);
      p1 = fmaf(qf[8 + i], bf2f((ushort)kb2[i]), p1);
    }
    float ea = __expf((p0 + p1) * 0.25f);
    ea = valid ? ea : 0.f;
    dsum += ea;
    #pragma unroll
    for (int i = 0; i < 8; ++i) {
      acc[i] = fmaf(ea, bf2f((ushort)va[i]), acc[i]);
      acc[8 + i] = fmaf(ea, bf2f((ushort)vb2[i]), acc[8 + i]);
    }
  }

  // reduce over the 8 e-lanes (lane bits 3..5)
  #pragma unroll
  for (int off = 8; off <= 32; off <<= 1) {
    dsum += __shfl_xor(dsum, off);
    #pragma unroll
    for (int i = 0; i < 16; ++i) acc[i] += __shfl_xor(acc[i], off);
  }
  if (lane < 8) {  // e == 0 lanes hold full sums for head h = lane
    #pragma unroll
    for (int i = 0; i < 16; i += 4)
      *(float4*)&lds_s[lane][i] = make_float4(acc[i], acc[i + 1], acc[i + 2], acc[i + 3]);
    lds_s[lane][16] = dsum;
  }
  __syncthreads();

  // epilogue: lane owns channels (2*lane, 2*lane+1)
  int c0 = lane * 2;
  int hh = lane >> 3, cc = (lane & 7) * 2;
  float2 ov = *(float2*)&lds_s[hh][cc];
  float den = lds_s[hh][16];
  float inv = 1.f / (den + 1e-16f);
  float o0 = ov.x * inv, o1 = ov.y * inv;

  ushort2 xru = *(const ushort2*)(xr + (size_t)n * DIM + c0);
  float xr0 = bf2f(xru.x), xr1 = bf2f(xru.y);
  float wa0 = wbeta[c0] + wbeta[2 * DIM + c0];
  float wa1 = wbeta[c0 + 1] + wbeta[2 * DIM + c0 + 1];
  float wb0 = wbeta[DIM + c0] - wbeta[2 * DIM + c0];
  float wb1 = wbeta[DIM + c0 + 1] - wbeta[2 * DIM + c0 + 1];
  float bs = o0 * wa0 + o1 * wa1 + xr0 * wb0 + xr1 * wb1;
  #pragma unroll
  for (int off = 1; off < 64; off <<= 1) bs += __shfl_xor(bs, off);
  float beta = 1.f / (1.f + __expf(-bs));
  float y0 = fmaxf(beta * xr0 + (1.f - beta) * o0, 0.f);
  float y1 = fmaxf(beta * xr1 + (1.f - beta) * o1, 0.f);
  float2 rv = *(const float2*)(xres + (size_t)n * DIM + c0);
  y0 += rv.x;
  y1 += rv.y;
  float s = y0 + y1;
  #pragma unroll
  for (int off = 1; off < 64; off <<= 1) s += __shfl_xor(s, off);
  float mu = s * (1.f / 128.f);
  float d0 = y0 - mu, d1 = y1 - mu;
  float vs = d0 * d0 + d1 * d1;
  #pragma unroll
  for (int off = 1; off < 64; off <<= 1) vs += __shfl_xor(vs, off);
  float rstd = rsqrtf(vs * (1.f / 128.f) + 1e-5f);
  float2 g = *(const float2*)(lng + c0);
  float2 b = *(const float2*)(lnb + c0);
  float out0 = d0 * rstd * g.x + b.x;
  float out1 = d1 * rstd * g.y + b.y;
  *(float2*)(xnext + (size_t)n * DIM + c0) = make_float2(out0, out1);
  ushort2 ob;
  ob.x = f2bf(out0);
  ob.y = f2bf(out1);
  *(ushort2*)(xnextb + (size_t)n * DIM + c0) = ob;
}

// ---------------- launch ----------------

extern "C" void kernel_launch(void* const* d_in, const int* in_sizes, int n_in,
                              void* d_out, int out_size, void* d_ws, size_t ws_size,
                              hipStream_t stream) {
  const float* x_in = (const float*)d_in[0];
  const int* ei = (const int*)d_in[1];
  const float* Wq = (const float*)d_in[2];
  const float* bq = (const float*)d_in[3];
  const float* Wk = (const float*)d_in[4];
  const float* bk = (const float*)d_in[5];
  const float* Wv = (const float*)d_in[6];
  const float* bv = (const float*)d_in[7];
  const float* Wsk = (const float*)d_in[8];
  const float* bsk = (const float*)d_in[9];
  const float* Wb = (const float*)d_in[10];
  const float* lng = (const float*)d_in[11];
  const float* lnb = (const float*)d_in[12];
  const float* Wout = (const float*)d_in[13];
  const float* bout = (const float*)d_in[14];
  float* out = (float*)d_out;

  char* p = (char*)d_ws;
  auto alloc = [&](size_t bytes) {
    char* r = p;
    p += (bytes + 255) & ~(size_t)255;
    return r;
  };
  const size_t NB2 = (size_t)N_NODES * DIM * 2;
  const size_t NB4 = (size_t)N_NODES * DIM * 4;
  ushort* xbb = (ushort*)alloc(NB2);
  ushort* qb = (ushort*)alloc(NB2);
  ushort* kb = (ushort*)alloc(NB2);
  ushort* vb = (ushort*)alloc(NB2);
  ushort* xrb = (ushort*)alloc(NB2);
  float* xf0 = (float*)alloc(NB4);
  float* xf1 = (float*)alloc(NB4);
  ushort* wt = (ushort*)alloc((size_t)13 * DIM * DIM * 2);
  int* rowptr = (int*)alloc((N_NODES + 1) * 4);
  int* degc = (int*)alloc(N_NODES * 4);
  int* blksum = (int*)alloc(64 * 4);
  int* csr_src = (int*)alloc(N_EDGES * 4);

  // CSR by dst (deterministic rowptr via 3-phase scan)
  zero_ints_kernel<<<(N_NODES + 255) / 256, 256, 0, stream>>>(degc, N_NODES);
  count_deg_kernel<<<(N_EDGES + 255) / 256, 256, 0, stream>>>(ei, degc);
  scan1_kernel<<<N_SCAN_BLKS, SCAN_BLK, 0, stream>>>(degc, rowptr, blksum);
  scan2_kernel<<<1, 64, 0, stream>>>(blksum, rowptr);
  scan3_kernel<<<N_SCAN_BLKS, SCAN_BLK, 0, stream>>>(rowptr, blksum);
  zero_ints_kernel<<<(N_NODES + 255) / 256, 256, 0, stream>>>(degc, N_NODES);
  scatter_kernel<<<(N_EDGES + 255) / 256, 256, 0, stream>>>(ei, rowptr, degc, csr_src);

  // casts
  cast_x_kernel<<<(N_NODES * DIM / 4 + 255) / 256, 256, 0, stream>>>(x_in, xbb,
                                                                     N_NODES * DIM / 4);
  cast_w_kernel<<<dim3(4, 4, 13), dim3(32, 8), 0, stream>>>(Wq, Wk, Wv, Wsk, Wout, wt);

  const int GX = (N_NODES + 63) / 64;  // 313
  const float* xres = x_in;
  float* xfbufs[NLAYER] = {xf0, xf1, xf0};
  for (int l = 0; l < NLAYER; ++l) {
    gemm_mfma_kernel<1><<<dim3(GX, 4), 256, 0, stream>>>(
        xbb, wt + (size_t)l * 4 * DIM * DIM,
        bq + (size_t)l * DIM, bk + (size_t)l * DIM, bv + (size_t)l * DIM,
        bsk + (size_t)l * DIM, qb, kb, vb, xrb);
    attn_fused_kernel<<<N_NODES, 64, 0, stream>>>(
        qb, kb, vb, xrb, xres, rowptr, csr_src,
        Wb + (size_t)l * 3 * DIM, lng + (size_t)l * DIM, lnb + (size_t)l * DIM,
        xfbufs[l], xbb);
    xres = xfbufs[l];
  }
  gemm_mfma_kernel<0><<<dim3(GX, 1), 256, 0, stream>>>(
      xbb, wt + (size_t)12 * DIM * DIM, bout, bout, bout, bout, out, out, out, out);
}

// Round 4
// 218.131 us; speedup vs baseline: 1.7625x; 1.1038x over previous
//
#include <hip/hip_runtime.h>

#define N_NODES 20000
#define N_EDGES 320000
#define DIM 128
#define NLAYER 3
#define SCAN_BLK 1024
#define N_SCAN_BLKS ((N_NODES + SCAN_BLK - 1) / SCAN_BLK)  // 20
#define LDS_STRIDE 136  // padded bf16 row stride: bank stride 4 -> ~2-way (free)

typedef __attribute__((ext_vector_type(8))) short short8;
typedef __attribute__((ext_vector_type(4))) float f32x4;

__device__ inline ushort f2bf(float f) {
  uint u = __float_as_uint(f);
  uint r = (u + 0x7fffu + ((u >> 16) & 1u)) >> 16;
  return (ushort)r;
}
__device__ inline float bf2f(ushort u) { return __uint_as_float(((uint)u) << 16); }

// ---------------- CSR build ----------------

__global__ void zero_ints_kernel(int* __restrict__ p, int n) {
  int i = blockIdx.x * 256 + threadIdx.x;
  if (i < n) p[i] = 0;
}

__global__ void count_deg_kernel(const int* __restrict__ ei, int* __restrict__ deg) {
  int e = blockIdx.x * 256 + threadIdx.x;
  if (e < N_EDGES) atomicAdd(&deg[ei[N_EDGES + e]], 1);
}

__global__ __launch_bounds__(SCAN_BLK) void scan1_kernel(const int* __restrict__ deg,
                                                         int* __restrict__ rowptr,
                                                         int* __restrict__ blksum) {
  __shared__ int wsum[16];
  int t = threadIdx.x, lane = t & 63, w = t >> 6;
  int i = blockIdx.x * SCAN_BLK + t;
  int val = (i < N_NODES) ? deg[i] : 0;
  int s = val;
  #pragma unroll
  for (int off = 1; off < 64; off <<= 1) {
    int u = __shfl_up(s, off);
    if (lane >= off) s += u;
  }
  if (lane == 63) wsum[w] = s;
  __syncthreads();
  if (t < 16) {
    int wv = wsum[t];
    int ss = wv;
    #pragma unroll
    for (int off = 1; off < 16; off <<= 1) {
      int u = __shfl_up(ss, off);
      if (t >= off) ss += u;
    }
    wsum[t] = ss - wv;
  }
  __syncthreads();
  int excl = wsum[w] + s - val;
  if (i < N_NODES) rowptr[i] = excl;
  if (t == SCAN_BLK - 1) blksum[blockIdx.x] = excl + val;
}

__global__ void scan2_kernel(int* __restrict__ blksum, int* __restrict__ rowptr) {
  int t = threadIdx.x;  // 64
  int val = (t < N_SCAN_BLKS) ? blksum[t] : 0;
  int s = val;
  #pragma unroll
  for (int off = 1; off < 64; off <<= 1) {
    int u = __shfl_up(s, off);
    if (t >= off) s += u;
  }
  if (t < N_SCAN_BLKS) blksum[t] = s - val;
  if (t == 63) rowptr[N_NODES] = s;
}

// adds block offsets AND zeroes the scatter cursor (saves one dispatch)
__global__ __launch_bounds__(SCAN_BLK) void scan3_kernel(int* __restrict__ rowptr,
                                                         const int* __restrict__ blksum,
                                                         int* __restrict__ degc) {
  int i = blockIdx.x * SCAN_BLK + threadIdx.x;
  if (i < N_NODES) {
    rowptr[i] += blksum[blockIdx.x];
    degc[i] = 0;
  }
}

__global__ void scatter_kernel(const int* __restrict__ ei, const int* __restrict__ rowptr,
                               int* __restrict__ cursor, int* __restrict__ csr_src) {
  int e = blockIdx.x * 256 + threadIdx.x;
  if (e < N_EDGES) {
    int d = ei[N_EDGES + e];
    int s = ei[e];
    int pos = atomicAdd(&cursor[d], 1);
    csr_src[rowptr[d] + pos] = s;
  }
}

// ---------------- casts ----------------

__global__ void cast_x_kernel(const float* __restrict__ x, ushort* __restrict__ xb, int n4) {
  int i = blockIdx.x * 256 + threadIdx.x;
  if (i < n4) {
    float4 f = ((const float4*)x)[i];
    ushort4 o;
    o.x = f2bf(f.x); o.y = f2bf(f.y); o.z = f2bf(f.z); o.w = f2bf(f.w);
    ((ushort4*)xb)[i] = o;
  }
}

__global__ void cast_w_kernel(const float* __restrict__ Wq, const float* __restrict__ Wk,
                              const float* __restrict__ Wv, const float* __restrict__ Ws,
                              const float* __restrict__ Wo, ushort* __restrict__ wt) {
  int z = blockIdx.z;
  const float* src;
  if (z < 12) {
    int l = z >> 2, j = z & 3;
    src = (j == 0 ? Wq : j == 1 ? Wk : j == 2 ? Wv : Ws) + (size_t)l * DIM * DIM;
  } else {
    src = Wo;
  }
  __shared__ float tile[32][33];
  int tx = threadIdx.x, ty = threadIdx.y;  // 32 x 8
  int k0 = blockIdx.x * 32, n0 = blockIdx.y * 32;
  #pragma unroll
  for (int i = 0; i < 32; i += 8)
    tile[ty + i][tx] = src[(size_t)(k0 + ty + i) * DIM + n0 + tx];
  __syncthreads();
  ushort* dst = wt + (size_t)z * DIM * DIM;
  #pragma unroll
  for (int i = 0; i < 32; i += 8)
    dst[(size_t)(n0 + ty + i) * DIM + k0 + tx] = f2bf(tile[tx][ty + i]);
}

// ---------------- bf16 MFMA GEMM: O_j = X @ W_j + b_j ----------------
// grid (ceil(M/128), nmat), block 256 = 4 waves in 2x2; wave tile 64x64.
// A tile (128x128 bf16) staged in LDS with coalesced loads + padded stride;
// B (the 32KB weight) read direct from global (L1/L2-resident across blocks).
template <int OUT_BF16>
__global__ __launch_bounds__(256) void gemm_mfma_kernel(
    const ushort* __restrict__ X, const ushort* __restrict__ WT,
    const float* __restrict__ B0, const float* __restrict__ B1,
    const float* __restrict__ B2, const float* __restrict__ B3,
    void* __restrict__ O0, void* __restrict__ O1, void* __restrict__ O2,
    void* __restrict__ O3) {
  __shared__ ushort As[128 * LDS_STRIDE];  // 34816 B
  int mat = blockIdx.y;
  const ushort* Wt = WT + (size_t)mat * DIM * DIM;
  const float* bias;
  void* O;
  switch (mat) {
    case 0: bias = B0; O = O0; break;
    case 1: bias = B1; O = O1; break;
    case 2: bias = B2; O = O2; break;
    default: bias = B3; O = O3; break;
  }
  int t = threadIdx.x;
  int wid = t >> 6, lane = t & 63;
  int row0 = blockIdx.x * 128;
  int wr = wid >> 1, wc = wid & 1;
  int lr = lane & 15;
  int kc8 = (lane >> 4) * 8;  // 0,8,16,24

  // ---- stage A tile: 8 passes x (256 thr x 16B) fully coalesced
  {
    int rowi = t >> 4;          // 16 threads per 256B row
    int col = (t & 15) * 8;     // bf16 elems
    #pragma unroll
    for (int pass = 0; pass < 8; ++pass) {
      int row = pass * 16 + rowi;
      int gr = min(row0 + row, N_NODES - 1);  // clamp; garbage rows never stored
      short8 val = *(const short8*)(X + (size_t)gr * DIM + col);
      *(short8*)(As + row * LDS_STRIDE + col) = val;
    }
  }
  __syncthreads();

  f32x4 acc[4][4];
  #pragma unroll
  for (int i = 0; i < 4; ++i)
    #pragma unroll
    for (int j = 0; j < 4; ++j) acc[i][j] = (f32x4){0.f, 0.f, 0.f, 0.f};

  #pragma unroll
  for (int ks = 0; ks < 4; ++ks) {
    short8 b[4];
    #pragma unroll
    for (int cf = 0; cf < 4; ++cf) {
      int c = wc * 64 + cf * 16 + lr;
      b[cf] = *(const short8*)(Wt + (size_t)c * DIM + ks * 32 + kc8);
    }
    #pragma unroll
    for (int rf = 0; rf < 4; ++rf) {
      int r = wr * 64 + rf * 16 + lr;
      short8 a = *(const short8*)(As + r * LDS_STRIDE + ks * 32 + kc8);
      #pragma unroll
      for (int cf = 0; cf < 4; ++cf)
        acc[rf][cf] = __builtin_amdgcn_mfma_f32_16x16x32_bf16(a, b[cf], acc[rf][cf], 0, 0, 0);
    }
  }

  // C/D layout: col = lane&15, row = (lane>>4)*4 + reg  [m89-verified]
  #pragma unroll
  for (int cf = 0; cf < 4; ++cf) {
    int c = wc * 64 + cf * 16 + lr;
    float bv = bias[c];
    #pragma unroll
    for (int rf = 0; rf < 4; ++rf) {
      #pragma unroll
      for (int reg = 0; reg < 4; ++reg) {
        int r = row0 + wr * 64 + rf * 16 + (lane >> 4) * 4 + reg;
        if (r < N_NODES) {
          float val = acc[rf][cf][reg] + bv;
          if (OUT_BF16)
            ((ushort*)O)[(size_t)r * DIM + c] = f2bf(val);
          else
            ((float*)O)[(size_t)r * DIM + c] = val;
        }
      }
    }
  }
}

// ---------------- fused attention + beta-skip + relu + residual + layernorm --------
__global__ __launch_bounds__(64) void attn_fused_kernel(
    const ushort* __restrict__ q, const ushort* __restrict__ k, const ushort* __restrict__ v,
    const ushort* __restrict__ xr, const float* __restrict__ xres,
    const int* __restrict__ rowptr, const int* __restrict__ csr_src,
    const float* __restrict__ wbeta, const float* __restrict__ lng,
    const float* __restrict__ lnb, float* __restrict__ xnext,
    ushort* __restrict__ xnextb) {
  __shared__ float lds_s[8][20];
  int n = blockIdx.x;
  int lane = threadIdx.x;
  int h = lane & 7, e = lane >> 3;

  const ushort* qrow = q + (size_t)n * DIM + h * 16;
  short8 q0 = *(const short8*)qrow;
  short8 q1 = *(const short8*)(qrow + 8);
  float qf[16];
  #pragma unroll
  for (int i = 0; i < 8; ++i) {
    qf[i] = bf2f((ushort)q0[i]);
    qf[8 + i] = bf2f((ushort)q1[i]);
  }

  int s0 = rowptr[n];
  int deg = rowptr[n + 1] - s0;
  float acc[16];
  #pragma unroll
  for (int i = 0; i < 16; ++i) acc[i] = 0.f;
  float dsum = 0.f;

  for (int base = 0; base < deg; base += 8) {
    int idx = base + e;
    bool valid = idx < deg;
    int src = csr_src[s0 + min(idx, deg - 1)];
    const ushort* kr = k + (size_t)src * DIM + h * 16;
    const ushort* vr = v + (size_t)src * DIM + h * 16;
    short8 ka = *(const short8*)kr;
    short8 kb2 = *(const short8*)(kr + 8);
    short8 va = *(const short8*)vr;
    short8 vb2 = *(const short8*)(vr + 8);
    float p0 = 0.f, p1 = 0.f;
    #pragma unroll
    for (int i = 0; i < 8; ++i) {
      p0 = fmaf(qf[i], bf2f((ushort)ka[i]), p0);
      p1 = fmaf(qf[8 + i], bf2f((ushort)kb2[i]), p1);
    }
    float ea = __expf((p0 + p1) * 0.25f);
    ea = valid ? ea : 0.f;
    dsum += ea;
    #pragma unroll
    for (int i = 0; i < 8; ++i) {
      acc[i] = fmaf(ea, bf2f((ushort)va[i]), acc[i]);
      acc[8 + i] = fmaf(ea, bf2f((ushort)vb2[i]), acc[8 + i]);
    }
  }

  #pragma unroll
  for (int off = 8; off <= 32; off <<= 1) {
    dsum += __shfl_xor(dsum, off);
    #pragma unroll
    for (int i = 0; i < 16; ++i) acc[i] += __shfl_xor(acc[i], off);
  }
  if (lane < 8) {
    #pragma unroll
    for (int i = 0; i < 16; i += 4)
      *(float4*)&lds_s[lane][i] = make_float4(acc[i], acc[i + 1], acc[i + 2], acc[i + 3]);
    lds_s[lane][16] = dsum;
  }
  __syncthreads();

  int c0 = lane * 2;
  int hh = lane >> 3, cc = (lane & 7) * 2;
  float2 ov = *(float2*)&lds_s[hh][cc];
  float den = lds_s[hh][16];
  float inv = 1.f / (den + 1e-16f);
  float o0 = ov.x * inv, o1 = ov.y * inv;

  ushort2 xru = *(const ushort2*)(xr + (size_t)n * DIM + c0);
  float xr0 = bf2f(xru.x), xr1 = bf2f(xru.y);
  float wa0 = wbeta[c0] + wbeta[2 * DIM + c0];
  float wa1 = wbeta[c0 + 1] + wbeta[2 * DIM + c0 + 1];
  float wb0 = wbeta[DIM + c0] - wbeta[2 * DIM + c0];
  float wb1 = wbeta[DIM + c0 + 1] - wbeta[2 * DIM + c0 + 1];
  float bs = o0 * wa0 + o1 * wa1 + xr0 * wb0 + xr1 * wb1;
  #pragma unroll
  for (int off = 1; off < 64; off <<= 1) bs += __shfl_xor(bs, off);
  float beta = 1.f / (1.f + __expf(-bs));
  float y0 = fmaxf(beta * xr0 + (1.f - beta) * o0, 0.f);
  float y1 = fmaxf(beta * xr1 + (1.f - beta) * o1, 0.f);
  float2 rv = *(const float2*)(xres + (size_t)n * DIM + c0);
  y0 += rv.x;
  y1 += rv.y;
  float s = y0 + y1;
  #pragma unroll
  for (int off = 1; off < 64; off <<= 1) s += __shfl_xor(s, off);
  float mu = s * (1.f / 128.f);
  float d0 = y0 - mu, d1 = y1 - mu;
  float vs = d0 * d0 + d1 * d1;
  #pragma unroll
  for (int off = 1; off < 64; off <<= 1) vs += __shfl_xor(vs, off);
  float rstd = rsqrtf(vs * (1.f / 128.f) + 1e-5f);
  float2 g = *(const float2*)(lng + c0);
  float2 b = *(const float2*)(lnb + c0);
  float out0 = d0 * rstd * g.x + b.x;
  float out1 = d1 * rstd * g.y + b.y;
  *(float2*)(xnext + (size_t)n * DIM + c0) = make_float2(out0, out1);
  ushort2 ob;
  ob.x = f2bf(out0);
  ob.y = f2bf(out1);
  *(ushort2*)(xnextb + (size_t)n * DIM + c0) = ob;
}

// ---------------- launch ----------------

extern "C" void kernel_launch(void* const* d_in, const int* in_sizes, int n_in,
                              void* d_out, int out_size, void* d_ws, size_t ws_size,
                              hipStream_t stream) {
  const float* x_in = (const float*)d_in[0];
  const int* ei = (const int*)d_in[1];
  const float* Wq = (const float*)d_in[2];
  const float* bq = (const float*)d_in[3];
  const float* Wk = (const float*)d_in[4];
  const float* bk = (const float*)d_in[5];
  const float* Wv = (const float*)d_in[6];
  const float* bv = (const float*)d_in[7];
  const float* Wsk = (const float*)d_in[8];
  const float* bsk = (const float*)d_in[9];
  const float* Wb = (const float*)d_in[10];
  const float* lng = (const float*)d_in[11];
  const float* lnb = (const float*)d_in[12];
  const float* Wout = (const float*)d_in[13];
  const float* bout = (const float*)d_in[14];
  float* out = (float*)d_out;

  char* p = (char*)d_ws;
  auto alloc = [&](size_t bytes) {
    char* r = p;
    p += (bytes + 255) & ~(size_t)255;
    return r;
  };
  const size_t NB2 = (size_t)N_NODES * DIM * 2;
  const size_t NB4 = (size_t)N_NODES * DIM * 4;
  ushort* xbb = (ushort*)alloc(NB2);
  ushort* qb = (ushort*)alloc(NB2);
  ushort* kb = (ushort*)alloc(NB2);
  ushort* vb = (ushort*)alloc(NB2);
  ushort* xrb = (ushort*)alloc(NB2);
  float* xf0 = (float*)alloc(NB4);
  float* xf1 = (float*)alloc(NB4);
  ushort* wt = (ushort*)alloc((size_t)13 * DIM * DIM * 2);
  int* rowptr = (int*)alloc((N_NODES + 1) * 4);
  int* degc = (int*)alloc(N_NODES * 4);
  int* blksum = (int*)alloc(64 * 4);
  int* csr_src = (int*)alloc(N_EDGES * 4);

  // CSR by dst
  zero_ints_kernel<<<(N_NODES + 255) / 256, 256, 0, stream>>>(degc, N_NODES);
  count_deg_kernel<<<(N_EDGES + 255) / 256, 256, 0, stream>>>(ei, degc);
  scan1_kernel<<<N_SCAN_BLKS, SCAN_BLK, 0, stream>>>(degc, rowptr, blksum);
  scan2_kernel<<<1, 64, 0, stream>>>(blksum, rowptr);
  scan3_kernel<<<N_SCAN_BLKS, SCAN_BLK, 0, stream>>>(rowptr, blksum, degc);
  scatter_kernel<<<(N_EDGES + 255) / 256, 256, 0, stream>>>(ei, rowptr, degc, csr_src);

  // casts
  cast_x_kernel<<<(N_NODES * DIM / 4 + 255) / 256, 256, 0, stream>>>(x_in, xbb,
                                                                     N_NODES * DIM / 4);
  cast_w_kernel<<<dim3(4, 4, 13), dim3(32, 8), 0, stream>>>(Wq, Wk, Wv, Wsk, Wout, wt);

  const int GX = (N_NODES + 127) / 128;  // 157
  const float* xres = x_in;
  float* xfbufs[NLAYER] = {xf0, xf1, xf0};
  for (int l = 0; l < NLAYER; ++l) {
    gemm_mfma_kernel<1><<<dim3(GX, 4), 256, 0, stream>>>(
        xbb, wt + (size_t)l * 4 * DIM * DIM,
        bq + (size_t)l * DIM, bk + (size_t)l * DIM, bv + (size_t)l * DIM,
        bsk + (size_t)l * DIM, qb, kb, vb, xrb);
    attn_fused_kernel<<<N_NODES, 64, 0, stream>>>(
        qb, kb, vb, xrb, xres, rowptr, csr_src,
        Wb + (size_t)l * 3 * DIM, lng + (size_t)l * DIM, lnb + (size_t)l * DIM,
        xfbufs[l], xbb);
    xres = xfbufs[l];
  }
  gemm_mfma_kernel<0><<<dim3(GX, 1), 256, 0, stream>>>(
      xbb, wt + (size_t)12 * DIM * DIM, bout, bout, bout, bout, out, out, out, out);
}

// Round 5
// 217.731 us; speedup vs baseline: 1.7657x; 1.0018x over previous
//
#include <hip/hip_runtime.h>

#define N_NODES 20000
#define N_EDGES 320000
#define DIM 128
#define NLAYER 3
#define SCAN_BLK 1024
#define N_SCAN_BLKS ((N_NODES + SCAN_BLK - 1) / SCAN_BLK)  // 20
#define LDS_STRIDE 136  // padded bf16 row stride: bank stride 4 -> ~2-way (free)

// prep kernel task ranges (256-thread blocks)
#define PREP_CASTX_BLKS 2500   // 20000*128/4 float4 = 640000 = 2500*256
#define PREP_CASTW_BLKS 208    // 13 mats * 16 (4x4 32-tiles)
#define PREP_ZERO_BLKS 79      // ceil(20000/256)
#define PREP_TOTAL (PREP_CASTX_BLKS + PREP_CASTW_BLKS + PREP_ZERO_BLKS)

typedef __attribute__((ext_vector_type(8))) short short8;
typedef __attribute__((ext_vector_type(4))) float f32x4;

__device__ inline ushort f2bf(float f) {
  uint u = __float_as_uint(f);
  uint r = (u + 0x7fffu + ((u >> 16) & 1u)) >> 16;
  return (ushort)r;
}
__device__ inline float bf2f(ushort u) { return __uint_as_float(((uint)u) << 16); }

// ---------------- fused prep: cast_x | cast_w | zero degc ----------------
__global__ __launch_bounds__(256) void prep_kernel(
    const float* __restrict__ x, ushort* __restrict__ xb,
    const float* __restrict__ Wq, const float* __restrict__ Wk,
    const float* __restrict__ Wv, const float* __restrict__ Ws,
    const float* __restrict__ Wo, ushort* __restrict__ wt,
    int* __restrict__ degc) {
  int b = blockIdx.x;
  int t = threadIdx.x;
  if (b < PREP_CASTX_BLKS) {
    int i = b * 256 + t;
    float4 f = ((const float4*)x)[i];
    ushort4 o;
    o.x = f2bf(f.x); o.y = f2bf(f.y); o.z = f2bf(f.z); o.w = f2bf(f.w);
    ((ushort4*)xb)[i] = o;
  } else if (b < PREP_CASTX_BLKS + PREP_CASTW_BLKS) {
    int idx = b - PREP_CASTX_BLKS;
    int z = idx >> 4;
    int r = idx & 15;
    int k0 = (r >> 2) * 32, n0 = (r & 3) * 32;
    const float* src;
    if (z < 12) {
      int l = z >> 2, j = z & 3;
      src = (j == 0 ? Wq : j == 1 ? Wk : j == 2 ? Wv : Ws) + (size_t)l * DIM * DIM;
    } else {
      src = Wo;
    }
    __shared__ float tile[32][33];
    int tx = t & 31, ty = t >> 5;  // 32 x 8
    #pragma unroll
    for (int i = 0; i < 32; i += 8)
      tile[ty + i][tx] = src[(size_t)(k0 + ty + i) * DIM + n0 + tx];
    __syncthreads();
    ushort* dst = wt + (size_t)z * DIM * DIM;
    #pragma unroll
    for (int i = 0; i < 32; i += 8)
      dst[(size_t)(n0 + ty + i) * DIM + k0 + tx] = f2bf(tile[tx][ty + i]);
  } else {
    int i = (b - PREP_CASTX_BLKS - PREP_CASTW_BLKS) * 256 + t;
    if (i < N_NODES) degc[i] = 0;
  }
}

// ---------------- CSR build ----------------

__global__ void count_deg_kernel(const int* __restrict__ ei, int* __restrict__ deg) {
  int e = blockIdx.x * 256 + threadIdx.x;
  if (e < N_EDGES) atomicAdd(&deg[ei[N_EDGES + e]], 1);
}

__global__ __launch_bounds__(SCAN_BLK) void scan1_kernel(const int* __restrict__ deg,
                                                         int* __restrict__ rowptr,
                                                         int* __restrict__ blksum) {
  __shared__ int wsum[16];
  int t = threadIdx.x, lane = t & 63, w = t >> 6;
  int i = blockIdx.x * SCAN_BLK + t;
  int val = (i < N_NODES) ? deg[i] : 0;
  int s = val;
  #pragma unroll
  for (int off = 1; off < 64; off <<= 1) {
    int u = __shfl_up(s, off);
    if (lane >= off) s += u;
  }
  if (lane == 63) wsum[w] = s;
  __syncthreads();
  if (t < 16) {
    int wv = wsum[t];
    int ss = wv;
    #pragma unroll
    for (int off = 1; off < 16; off <<= 1) {
      int u = __shfl_up(ss, off);
      if (t >= off) ss += u;
    }
    wsum[t] = ss - wv;
  }
  __syncthreads();
  int excl = wsum[w] + s - val;
  if (i < N_NODES) rowptr[i] = excl;
  if (t == SCAN_BLK - 1) blksum[blockIdx.x] = excl + val;
}

__global__ void scan2_kernel(int* __restrict__ blksum, int* __restrict__ rowptr) {
  int t = threadIdx.x;  // 64
  int val = (t < N_SCAN_BLKS) ? blksum[t] : 0;
  int s = val;
  #pragma unroll
  for (int off = 1; off < 64; off <<= 1) {
    int u = __shfl_up(s, off);
    if (t >= off) s += u;
  }
  if (t < N_SCAN_BLKS) blksum[t] = s - val;
  if (t == 63) rowptr[N_NODES] = s;
}

__global__ __launch_bounds__(SCAN_BLK) void scan3_kernel(int* __restrict__ rowptr,
                                                         const int* __restrict__ blksum,
                                                         int* __restrict__ degc) {
  int i = blockIdx.x * SCAN_BLK + threadIdx.x;
  if (i < N_NODES) {
    rowptr[i] += blksum[blockIdx.x];
    degc[i] = 0;
  }
}

__global__ void scatter_kernel(const int* __restrict__ ei, const int* __restrict__ rowptr,
                               int* __restrict__ cursor, int* __restrict__ csr_src) {
  int e = blockIdx.x * 256 + threadIdx.x;
  if (e < N_EDGES) {
    int d = ei[N_EDGES + e];
    int s = ei[e];
    int pos = atomicAdd(&cursor[d], 1);
    csr_src[rowptr[d] + pos] = s;
  }
}

// ---------------- bf16 MFMA GEMM: O_j = X @ W_j + b_j ----------------
// grid (ceil(M/128), nmat), block 256 = 4 waves in 2x2; wave tile 64x64.
// A tile staged in LDS (coalesced, padded stride); B direct from global.
// Per-mat output pointer + row stride (for the kv-interleaved layout).
template <int OUT_BF16>
__global__ __launch_bounds__(256) void gemm_mfma_kernel(
    const ushort* __restrict__ X, const ushort* __restrict__ WT,
    const float* __restrict__ B0, const float* __restrict__ B1,
    const float* __restrict__ B2, const float* __restrict__ B3,
    void* __restrict__ O0, void* __restrict__ O1, void* __restrict__ O2,
    void* __restrict__ O3, int st0, int st1, int st2, int st3) {
  __shared__ ushort As[128 * LDS_STRIDE];  // 34816 B
  int mat = blockIdx.y;
  const ushort* Wt = WT + (size_t)mat * DIM * DIM;
  const float* bias;
  void* O;
  int ost;
  switch (mat) {
    case 0: bias = B0; O = O0; ost = st0; break;
    case 1: bias = B1; O = O1; ost = st1; break;
    case 2: bias = B2; O = O2; ost = st2; break;
    default: bias = B3; O = O3; ost = st3; break;
  }
  int t = threadIdx.x;
  int wid = t >> 6, lane = t & 63;
  int row0 = blockIdx.x * 128;
  int wr = wid >> 1, wc = wid & 1;
  int lr = lane & 15;
  int kc8 = (lane >> 4) * 8;

  {
    int rowi = t >> 4;
    int col = (t & 15) * 8;
    #pragma unroll
    for (int pass = 0; pass < 8; ++pass) {
      int row = pass * 16 + rowi;
      int gr = min(row0 + row, N_NODES - 1);
      short8 val = *(const short8*)(X + (size_t)gr * DIM + col);
      *(short8*)(As + row * LDS_STRIDE + col) = val;
    }
  }
  __syncthreads();

  f32x4 acc[4][4];
  #pragma unroll
  for (int i = 0; i < 4; ++i)
    #pragma unroll
    for (int j = 0; j < 4; ++j) acc[i][j] = (f32x4){0.f, 0.f, 0.f, 0.f};

  #pragma unroll
  for (int ks = 0; ks < 4; ++ks) {
    short8 b[4];
    #pragma unroll
    for (int cf = 0; cf < 4; ++cf) {
      int c = wc * 64 + cf * 16 + lr;
      b[cf] = *(const short8*)(Wt + (size_t)c * DIM + ks * 32 + kc8);
    }
    #pragma unroll
    for (int rf = 0; rf < 4; ++rf) {
      int r = wr * 64 + rf * 16 + lr;
      short8 a = *(const short8*)(As + r * LDS_STRIDE + ks * 32 + kc8);
      #pragma unroll
      for (int cf = 0; cf < 4; ++cf)
        acc[rf][cf] = __builtin_amdgcn_mfma_f32_16x16x32_bf16(a, b[cf], acc[rf][cf], 0, 0, 0);
    }
  }

  #pragma unroll
  for (int cf = 0; cf < 4; ++cf) {
    int c = wc * 64 + cf * 16 + lr;
    float bv = bias[c];
    #pragma unroll
    for (int rf = 0; rf < 4; ++rf) {
      #pragma unroll
      for (int reg = 0; reg < 4; ++reg) {
        int r = row0 + wr * 64 + rf * 16 + (lane >> 4) * 4 + reg;
        if (r < N_NODES) {
          float val = acc[rf][cf][reg] + bv;
          if (OUT_BF16)
            ((ushort*)O)[(size_t)r * ost + c] = f2bf(val);
          else
            ((float*)O)[(size_t)r * ost + c] = val;
        }
      }
    }
  }
}

// ---------------- fused attention + beta-skip + relu + residual + layernorm --------
// 256-thread blocks, 4 waves, one dst node per wave. kv interleaved:
// kv[node][0..127] = k, kv[node][128..255] = v (one 512B region per edge).
__global__ __launch_bounds__(256) void attn_fused_kernel(
    const ushort* __restrict__ q, const ushort* __restrict__ kv,
    const ushort* __restrict__ xr, const float* __restrict__ xres,
    const int* __restrict__ rowptr, const int* __restrict__ csr_src,
    const float* __restrict__ wbeta, const float* __restrict__ lng,
    const float* __restrict__ lnb, float* __restrict__ xnext,
    ushort* __restrict__ xnextb) {
  __shared__ float lds_s[4][8][20];
  int w = threadIdx.x >> 6;
  int lane = threadIdx.x & 63;
  int n = blockIdx.x * 4 + w;
  int h = lane & 7, e = lane >> 3;

  const ushort* qrow = q + (size_t)n * DIM + h * 16;
  short8 q0 = *(const short8*)qrow;
  short8 q1 = *(const short8*)(qrow + 8);
  float qf[16];
  #pragma unroll
  for (int i = 0; i < 8; ++i) {
    qf[i] = bf2f((ushort)q0[i]);
    qf[8 + i] = bf2f((ushort)q1[i]);
  }

  int s0 = rowptr[n];
  int deg = rowptr[n + 1] - s0;
  float acc[16];
  #pragma unroll
  for (int i = 0; i < 16; ++i) acc[i] = 0.f;
  float dsum = 0.f;

  for (int base = 0; base < deg; base += 8) {
    int idx = base + e;
    bool valid = idx < deg;
    int src = csr_src[s0 + min(idx, deg - 1)];
    const ushort* kr = kv + (size_t)src * 256 + h * 16;
    short8 ka = *(const short8*)kr;
    short8 kb2 = *(const short8*)(kr + 8);
    short8 va = *(const short8*)(kr + 128);
    short8 vb2 = *(const short8*)(kr + 136);
    float p0 = 0.f, p1 = 0.f;
    #pragma unroll
    for (int i = 0; i < 8; ++i) {
      p0 = fmaf(qf[i], bf2f((ushort)ka[i]), p0);
      p1 = fmaf(qf[8 + i], bf2f((ushort)kb2[i]), p1);
    }
    float ea = __expf((p0 + p1) * 0.25f);
    ea = valid ? ea : 0.f;
    dsum += ea;
    #pragma unroll
    for (int i = 0; i < 8; ++i) {
      acc[i] = fmaf(ea, bf2f((ushort)va[i]), acc[i]);
      acc[8 + i] = fmaf(ea, bf2f((ushort)vb2[i]), acc[8 + i]);
    }
  }

  #pragma unroll
  for (int off = 8; off <= 32; off <<= 1) {
    dsum += __shfl_xor(dsum, off);
    #pragma unroll
    for (int i = 0; i < 16; ++i) acc[i] += __shfl_xor(acc[i], off);
  }
  if (lane < 8) {
    #pragma unroll
    for (int i = 0; i < 16; i += 4)
      *(float4*)&lds_s[w][lane][i] = make_float4(acc[i], acc[i + 1], acc[i + 2], acc[i + 3]);
    lds_s[w][lane][16] = dsum;
  }
  __syncthreads();

  int c0 = lane * 2;
  int hh = lane >> 3, cc = (lane & 7) * 2;
  float2 ov = *(float2*)&lds_s[w][hh][cc];
  float den = lds_s[w][hh][16];
  float inv = 1.f / (den + 1e-16f);
  float o0 = ov.x * inv, o1 = ov.y * inv;

  ushort2 xru = *(const ushort2*)(xr + (size_t)n * DIM + c0);
  float xr0 = bf2f(xru.x), xr1 = bf2f(xru.y);
  float wa0 = wbeta[c0] + wbeta[2 * DIM + c0];
  float wa1 = wbeta[c0 + 1] + wbeta[2 * DIM + c0 + 1];
  float wb0 = wbeta[DIM + c0] - wbeta[2 * DIM + c0];
  float wb1 = wbeta[DIM + c0 + 1] - wbeta[2 * DIM + c0 + 1];
  float bs = o0 * wa0 + o1 * wa1 + xr0 * wb0 + xr1 * wb1;
  #pragma unroll
  for (int off = 1; off < 64; off <<= 1) bs += __shfl_xor(bs, off);
  float beta = 1.f / (1.f + __expf(-bs));
  float y0 = fmaxf(beta * xr0 + (1.f - beta) * o0, 0.f);
  float y1 = fmaxf(beta * xr1 + (1.f - beta) * o1, 0.f);
  float2 rv = *(const float2*)(xres + (size_t)n * DIM + c0);
  y0 += rv.x;
  y1 += rv.y;
  float s = y0 + y1;
  #pragma unroll
  for (int off = 1; off < 64; off <<= 1) s += __shfl_xor(s, off);
  float mu = s * (1.f / 128.f);
  float d0 = y0 - mu, d1 = y1 - mu;
  float vs = d0 * d0 + d1 * d1;
  #pragma unroll
  for (int off = 1; off < 64; off <<= 1) vs += __shfl_xor(vs, off);
  float rstd = rsqrtf(vs * (1.f / 128.f) + 1e-5f);
  float2 g = *(const float2*)(lng + c0);
  float2 b = *(const float2*)(lnb + c0);
  float out0 = d0 * rstd * g.x + b.x;
  float out1 = d1 * rstd * g.y + b.y;
  *(float2*)(xnext + (size_t)n * DIM + c0) = make_float2(out0, out1);
  ushort2 ob;
  ob.x = f2bf(out0);
  ob.y = f2bf(out1);
  *(ushort2*)(xnextb + (size_t)n * DIM + c0) = ob;
}

// ---------------- launch ----------------

extern "C" void kernel_launch(void* const* d_in, const int* in_sizes, int n_in,
                              void* d_out, int out_size, void* d_ws, size_t ws_size,
                              hipStream_t stream) {
  const float* x_in = (const float*)d_in[0];
  const int* ei = (const int*)d_in[1];
  const float* Wq = (const float*)d_in[2];
  const float* bq = (const float*)d_in[3];
  const float* Wk = (const float*)d_in[4];
  const float* bk = (const float*)d_in[5];
  const float* Wv = (const float*)d_in[6];
  const float* bv = (const float*)d_in[7];
  const float* Wsk = (const float*)d_in[8];
  const float* bsk = (const float*)d_in[9];
  const float* Wb = (const float*)d_in[10];
  const float* lng = (const float*)d_in[11];
  const float* lnb = (const float*)d_in[12];
  const float* Wout = (const float*)d_in[13];
  const float* bout = (const float*)d_in[14];
  float* out = (float*)d_out;

  char* p = (char*)d_ws;
  auto alloc = [&](size_t bytes) {
    char* r = p;
    p += (bytes + 255) & ~(size_t)255;
    return r;
  };
  const size_t NB2 = (size_t)N_NODES * DIM * 2;
  const size_t NB4 = (size_t)N_NODES * DIM * 4;
  ushort* xbb = (ushort*)alloc(NB2);
  ushort* qb = (ushort*)alloc(NB2);
  ushort* kvb = (ushort*)alloc(NB2 * 2);  // interleaved [node][k:128 | v:128]
  ushort* xrb = (ushort*)alloc(NB2);
  float* xf0 = (float*)alloc(NB4);
  float* xf1 = (float*)alloc(NB4);
  ushort* wt = (ushort*)alloc((size_t)13 * DIM * DIM * 2);
  int* rowptr = (int*)alloc((N_NODES + 1) * 4);
  int* degc = (int*)alloc(N_NODES * 4);
  int* blksum = (int*)alloc(64 * 4);
  int* csr_src = (int*)alloc(N_EDGES * 4);

  // prep (cast_x | cast_w | zero degc) — independent tasks, one dispatch
  prep_kernel<<<PREP_TOTAL, 256, 0, stream>>>(x_in, xbb, Wq, Wk, Wv, Wsk, Wout, wt, degc);

  // CSR by dst
  count_deg_kernel<<<(N_EDGES + 255) / 256, 256, 0, stream>>>(ei, degc);
  scan1_kernel<<<N_SCAN_BLKS, SCAN_BLK, 0, stream>>>(degc, rowptr, blksum);
  scan2_kernel<<<1, 64, 0, stream>>>(blksum, rowptr);
  scan3_kernel<<<N_SCAN_BLKS, SCAN_BLK, 0, stream>>>(rowptr, blksum, degc);
  scatter_kernel<<<(N_EDGES + 255) / 256, 256, 0, stream>>>(ei, rowptr, degc, csr_src);

  const int GX = (N_NODES + 127) / 128;  // 157
  const float* xres = x_in;
  float* xfbufs[NLAYER] = {xf0, xf1, xf0};
  for (int l = 0; l < NLAYER; ++l) {
    gemm_mfma_kernel<1><<<dim3(GX, 4), 256, 0, stream>>>(
        xbb, wt + (size_t)l * 4 * DIM * DIM,
        bq + (size_t)l * DIM, bk + (size_t)l * DIM, bv + (size_t)l * DIM,
        bsk + (size_t)l * DIM,
        qb, kvb, kvb + 128, xrb, DIM, 256, 256, DIM);
    attn_fused_kernel<<<N_NODES / 4, 256, 0, stream>>>(
        qb, kvb, xrb, xres, rowptr, csr_src,
        Wb + (size_t)l * 3 * DIM, lng + (size_t)l * DIM, lnb + (size_t)l * DIM,
        xfbufs[l], xbb);
    xres = xfbufs[l];
  }
  gemm_mfma_kernel<0><<<dim3(GX, 1), 256, 0, stream>>>(
      xbb, wt + (size_t)12 * DIM * DIM, bout, bout, bout, bout,
      out, out, out, out, DIM, DIM, DIM, DIM);
}